// Round 13
// baseline (534.756 us; speedup 1.0000x reference)
//
#include <hip/hip_runtime.h>

// GIN encoder: N=100k, E=3.2M, G=512, H=64, L=3.
// Round 13: kill the BN atomic tails in mlp_mfma. R11->R12 delta (1563-deep
// fp32 atomic chains -> 391-deep = 69.5 -> ~40us) indicts the serialized
// atomicAdd chain (~200cyc/link) as the mlp tail. Now: per-block partials to
// private global slots (plain stores) + 1-block bn_reduce kernel. mlp grid
// back to 782 blocks (~3/CU). Rest identical to R12 (agg64_bn fused,
// scatter_sort, bucket_csr v3 src-block-sorted, bn_pool_out).

#define NBMAX 1024
#define CAP 4608
#define CHUNK 8192
#define NBLK_MAX 512
#define MSTR 72   // mids stride in shorts (9 uint4, bank-staggered)

typedef __attribute__((ext_vector_type(8))) short bf16x8;
typedef __attribute__((ext_vector_type(4))) float f32x4;

static __device__ __forceinline__ bf16x8 as_bf16x8(uint4 u) {
    union { uint4 a; bf16x8 b; } x; x.a = u; return x.b;
}
static __device__ __forceinline__ unsigned short bf16r(float v) {
    unsigned u = __float_as_uint(v);
    return (unsigned short)((u + 0x7FFFu + ((u >> 16) & 1u)) >> 16);
}
static __device__ __forceinline__ unsigned bf16pack2(float a, float b) {
    return (unsigned)bf16r(a) | ((unsigned)bf16r(b) << 16);
}

// ---- weight prep: bf16, transposed to [col][k] ----
__global__ void prep_weights(const float* __restrict__ w1_0, const float* __restrict__ w1_r,
                             const float* __restrict__ w2, unsigned short* __restrict__ w1T0,
                             unsigned short* __restrict__ w1T, unsigned short* __restrict__ w2T) {
    int t = blockIdx.x * 256 + threadIdx.x;
    if (t < 64 * 32) {
        int c = t >> 5, k = t & 31;
        w1T0[t] = bf16r(k < 3 ? w1_0[k * 64 + c] : 0.f);
    }
    if (t < 2 * 64 * 64) {
        int l = t >> 12, r = t & 4095, c = r >> 6, k = r & 63;
        w1T[t] = bf16r(w1_r[l * 4096 + k * 64 + c]);
    }
    if (t < 3 * 64 * 64) {
        int l = t >> 12, r = t & 4095, c = r >> 6, k = r & 63;
        w2T[t] = bf16r(w2[l * 4096 + k * 64 + c]);
    }
}

// ---- scatter_sort: block counting-sorts its 8192-edge chunk by bucket ----
__global__ __launch_bounds__(512) void scatter_sort(
    const int* __restrict__ src, const int* __restrict__ dst,
    int* __restrict__ bucketed2, int* __restrict__ offsTab, int E) {
    __shared__ int hist[NBMAX];
    __shared__ int offs[NBMAX];
    __shared__ int stage[CHUNK];
    int t = threadIdx.x, blk = blockIdx.x;
    int e0 = blk * CHUNK, e1 = min(e0 + CHUNK, E);
    int len = e1 - e0;
    hist[t] = 0; hist[t + 512] = 0;
    __syncthreads();
    for (int e = e0 + t; e < e1; e += 512) atomicAdd(&hist[dst[e] >> 7], 1);
    __syncthreads();
    offs[t] = hist[t]; offs[t + 512] = hist[t + 512];
    __syncthreads();
    for (int off = 1; off < 1024; off <<= 1) {
        int v0 = (t >= off) ? offs[t - off] : 0;
        int v1 = offs[t + 512 - off];
        __syncthreads();
        offs[t] += v0;
        offs[t + 512] += v1;
        __syncthreads();
    }
    offs[t] -= hist[t]; offs[t + 512] -= hist[t + 512];
    hist[t] = 0; hist[t + 512] = 0;
    __syncthreads();
    offsTab[blk * 1025 + t] = offs[t];
    offsTab[blk * 1025 + t + 512] = offs[t + 512];
    if (t == 0) offsTab[blk * 1025 + 1024] = len;
    for (int e = e0 + t; e < e1; e += 512) {
        int d = dst[e];
        int bk = d >> 7;
        int r = offs[bk] + atomicAdd(&hist[bk], 1);
        stage[r] = src[e] | ((d & 127) << 20);
    }
    __syncthreads();
    for (int j = t; j < len; j += 512) bucketed2[e0 + j] = stage[j];
}

// ---- bucket_csr v3: binsearch run-gather, counting sort by src-block, then
// by row -> CSR with ~src-ascending rows (L2 locality for agg) ----
__global__ __launch_bounds__(256) void bucket_csr(
    const int* __restrict__ bucketed2, const int* __restrict__ offsTab,
    int* __restrict__ csrOut, int* __restrict__ rowstart, int* __restrict__ rowend,
    int N, int nblk) {
    __shared__ int ein[CAP];
    __shared__ int emid[CAP];
    __shared__ int runs[NBLK_MAX];
    __shared__ int rbeg[NBLK_MAX];
    __shared__ int hist[128];
    __shared__ int base[129];
    int b = blockIdx.x, t = threadIdx.x, node0 = b << 7;
    for (int r = t; r < NBLK_MAX; r += 256) {
        int l = 0, g0 = 0;
        if (r < nblk) {
            int beg = offsTab[r * 1025 + b];
            int end = offsTab[r * 1025 + b + 1];
            l = end - beg;
            g0 = r * CHUNK + beg;
        }
        runs[r] = l;
        rbeg[r] = g0;
    }
    __syncthreads();
    for (int off = 1; off < NBLK_MAX; off <<= 1) {
        int v0 = (t >= off) ? runs[t - off] : 0;
        int v1 = (t + 256 >= off) ? runs[t + 256 - off] : 0;
        __syncthreads();
        runs[t] += v0;
        runs[t + 256] += v1;
        __syncthreads();
    }
    int cnt = min(runs[NBLK_MAX - 1], CAP);
    for (int j = t; j < cnt; j += 256) {
        int lo = 0, hi = nblk - 1;
        while (lo < hi) {
            int m = (lo + hi) >> 1;
            if (runs[m] > j) hi = m; else lo = m + 1;
        }
        int st = lo ? runs[lo - 1] : 0;
        ein[j] = bucketed2[rbeg[lo] + (j - st)];
    }
    // pass 1: group by src block (src>>10)
    if (t < 128) hist[t] = 0;
    __syncthreads();
    for (int j = t; j < cnt; j += 256) atomicAdd(&hist[(ein[j] & 0xFFFFF) >> 10], 1);
    __syncthreads();
    if (t < 128) base[t + 1] = hist[t];
    if (t == 0) base[0] = 0;
    __syncthreads();
    for (int off = 1; off < 128; off <<= 1) {
        int v = 0;
        if (t < 128 && (t + 1) > off) v = base[t + 1 - off];
        __syncthreads();
        if (t < 128 && (t + 1) > off) base[t + 1] += v;
        __syncthreads();
    }
    if (t < 128) hist[t] = 0;
    __syncthreads();
    for (int j = t; j < cnt; j += 256) {
        int p = ein[j];
        int sb = (p & 0xFFFFF) >> 10;
        int pos = base[sb] + atomicAdd(&hist[sb], 1);
        emid[pos] = p;
    }
    __syncthreads();
    // pass 2: counting sort by row
    if (t < 128) hist[t] = 0;
    __syncthreads();
    for (int j = t; j < cnt; j += 256) atomicAdd(&hist[emid[j] >> 20], 1);
    __syncthreads();
    if (t < 128) base[t + 1] = hist[t];
    if (t == 0) base[0] = 0;
    __syncthreads();
    for (int off = 1; off < 128; off <<= 1) {
        int v = 0;
        if (t < 128 && (t + 1) > off) v = base[t + 1 - off];
        __syncthreads();
        if (t < 128 && (t + 1) > off) base[t + 1] += v;
        __syncthreads();
    }
    if (t < 128) {
        int n = node0 + t;
        if (n < N) {
            rowstart[n] = b * CAP + base[t];
            rowend[n] = b * CAP + base[t + 1];
        }
        hist[t] = 0;
    }
    __syncthreads();
    for (int j = t; j < cnt; j += 256) {
        int p = emid[j];
        int local = p >> 20;
        int pos = base[local] + atomicAdd(&hist[local], 1);
        ein[pos] = p & 0xFFFFF;
    }
    __syncthreads();
    for (int j = t; j < cnt; j += 256) csrOut[b * CAP + j] = ein[j];
}

// ---- layer-0 agg (d=3): writes bf16 [n][8]-padded rows (uint4/node) ----
__global__ void agg3(const float* __restrict__ x, const int* __restrict__ rowstart,
                     const int* __restrict__ rowend, const int* __restrict__ csr,
                     uint4* __restrict__ out, int N) {
    int n = blockIdx.x * blockDim.x + threadIdx.x;
    if (n >= N) return;
    float a0 = x[n * 3], a1 = x[n * 3 + 1], a2 = x[n * 3 + 2];
    float b0 = 0.f, b1 = 0.f, b2 = 0.f;
    float c0 = 0.f, c1 = 0.f, c2 = 0.f;
    float d0 = 0.f, d1 = 0.f, d2 = 0.f;
    int s = rowstart[n], e = rowend[n];
    int j = s;
    for (; j + 3 < e; j += 4) {
        int i0 = csr[j], i1 = csr[j + 1], i2 = csr[j + 2], i3 = csr[j + 3];
        a0 += x[i0 * 3]; a1 += x[i0 * 3 + 1]; a2 += x[i0 * 3 + 2];
        b0 += x[i1 * 3]; b1 += x[i1 * 3 + 1]; b2 += x[i1 * 3 + 2];
        c0 += x[i2 * 3]; c1 += x[i2 * 3 + 1]; c2 += x[i2 * 3 + 2];
        d0 += x[i3 * 3]; d1 += x[i3 * 3 + 1]; d2 += x[i3 * 3 + 2];
    }
    for (; j < e; j++) {
        int nb = csr[j];
        a0 += x[nb * 3]; a1 += x[nb * 3 + 1]; a2 += x[nb * 3 + 2];
    }
    float s0 = a0 + b0 + c0 + d0, s1 = a1 + b1 + c1 + d1, s2 = a2 + b2 + c2 + d2;
    out[n] = make_uint4(bf16pack2(s0, s1), bf16pack2(s2, 0.f), 0u, 0u);
}

// bf16x2-packed accumulate of relu(v*sc+sh)
__device__ __forceinline__ void accum_bf16(const uint4 u,
                                           const float4 scA, const float4 scB,
                                           const float4 shA, const float4 shB,
                                           float* __restrict__ a) {
    a[0] += fmaxf(__uint_as_float(u.x << 16) * scA.x + shA.x, 0.f);
    a[1] += fmaxf(__uint_as_float(u.x & 0xFFFF0000u) * scA.y + shA.y, 0.f);
    a[2] += fmaxf(__uint_as_float(u.y << 16) * scA.z + shA.z, 0.f);
    a[3] += fmaxf(__uint_as_float(u.y & 0xFFFF0000u) * scA.w + shA.w, 0.f);
    a[4] += fmaxf(__uint_as_float(u.z << 16) * scB.x + shB.x, 0.f);
    a[5] += fmaxf(__uint_as_float(u.z & 0xFFFF0000u) * scB.y + shB.y, 0.f);
    a[6] += fmaxf(__uint_as_float(u.w << 16) * scB.z + shB.z, 0.f);
    a[7] += fmaxf(__uint_as_float(u.w & 0xFFFF0000u) * scB.w + shB.w, 0.f);
}

// ---- layers 1-2 agg + fused BN apply; bf16 in, bf16 out ----
__global__ __launch_bounds__(256) void agg64_bn(
    const unsigned short* __restrict__ h, const int* __restrict__ rowstart,
    const int* __restrict__ rowend, const int* __restrict__ csr,
    const float* __restrict__ bnsum, const float* __restrict__ bnsq,
    const float* __restrict__ gamma, const float* __restrict__ beta,
    uint4* __restrict__ out, int N) {
    __shared__ float scs[64], shs[64];
    int t = threadIdx.x;
    if (t < 64) {
        float mu = bnsum[t] / (float)N;
        float var = bnsq[t] / (float)N - mu * mu;
        float s = gamma[t] * rsqrtf(var + 1e-5f);
        scs[t] = s;
        shs[t] = beta[t] - mu * s;
    }
    __syncthreads();
    int g = t >> 3, l = t & 7;
    int n = blockIdx.x * 32 + g;
    if (n >= N) return;
    int c0 = l * 8;
    float4 scA = *(const float4*)&scs[c0], scB = *(const float4*)&scs[c0 + 4];
    float4 shA = *(const float4*)&shs[c0], shB = *(const float4*)&shs[c0 + 4];
    const uint4* hr = (const uint4*)h;
    float A[8] = {0,0,0,0,0,0,0,0};
    float B[8] = {0,0,0,0,0,0,0,0};
    uint4 self = hr[(size_t)n * 8 + l];
    accum_bf16(self, scA, scB, shA, shB, A);
    int s = rowstart[n], e = rowend[n];
    int j = s;
    for (; j + 3 < e; j += 4) {
        int i0 = csr[j], i1 = csr[j + 1], i2 = csr[j + 2], i3 = csr[j + 3];
        uint4 w0 = hr[(size_t)i0 * 8 + l];
        uint4 w1 = hr[(size_t)i1 * 8 + l];
        uint4 w2 = hr[(size_t)i2 * 8 + l];
        uint4 w3 = hr[(size_t)i3 * 8 + l];
        accum_bf16(w0, scA, scB, shA, shB, A);
        accum_bf16(w1, scA, scB, shA, shB, B);
        accum_bf16(w2, scA, scB, shA, shB, A);
        accum_bf16(w3, scA, scB, shA, shB, B);
    }
    for (; j < e; j++) {
        uint4 w = hr[(size_t)csr[j] * 8 + l];
        accum_bf16(w, scA, scB, shA, shB, A);
    }
    uint4 o;
    o.x = bf16pack2(A[0] + B[0], A[1] + B[1]);
    o.y = bf16pack2(A[2] + B[2], A[3] + B[3]);
    o.z = bf16pack2(A[4] + B[4], A[5] + B[5]);
    o.w = bf16pack2(A[6] + B[6], A[7] + B[7]);
    out[(size_t)n * 8 + l] = o;
}

// ---- MLP on MFMA v4: grid-stride tiles, weights in registers, coalesced
// LDS-staged epilogue, BN partials -> private global slots (NO atomics) ----
template <bool L0>
__global__ __launch_bounds__(256) void mlp_mfma(
    const uint4* __restrict__ actIn,
    uint4* __restrict__ houtU4,
    const uint4* __restrict__ w1Tu,
    const float* __restrict__ b1,
    const uint4* __restrict__ w2Tu,
    const float* __restrict__ b2,
    float* __restrict__ partS, float* __restrict__ partQ, int N, int nTiles) {
    __shared__ __align__(16) unsigned short mids[64 * MSTR];
    __shared__ float red[16][64];
    int t = threadIdx.x;
    int w = t >> 6, l = t & 63;
    int m16 = l & 15, q = l >> 4;
    const uint4 z4 = make_uint4(0, 0, 0, 0);
    bf16x8 w1f[4][2], w2f[4][2];
    float bias1[4], bias2[4];
#pragma unroll
    for (int c = 0; c < 4; c++) {
        int col = c * 16 + m16;
        if (L0) {
            w1f[c][0] = as_bf16x8(w1Tu[col * 4 + q]);
        } else {
            w1f[c][0] = as_bf16x8(w1Tu[col * 8 + q]);
            w1f[c][1] = as_bf16x8(w1Tu[col * 8 + 4 + q]);
        }
        w2f[c][0] = as_bf16x8(w2Tu[col * 8 + q]);
        w2f[c][1] = as_bf16x8(w2Tu[col * 8 + 4 + q]);
        bias1[c] = b1[col];
        bias2[c] = b2[col];
    }
    float s[4] = {0, 0, 0, 0}, sq[4] = {0, 0, 0, 0};
    for (int tile = blockIdx.x; tile < nTiles; tile += gridDim.x) {
        int base = tile * 64;
        __syncthreads();  // protect mids vs previous iteration's store loop
        int rA = base + w * 16 + m16;
        bf16x8 a0, a1;
        if (L0) {
            a0 = as_bf16x8((rA < N && q == 0) ? actIn[rA] : z4);
        } else {
            a0 = as_bf16x8(rA < N ? actIn[(size_t)rA * 8 + q] : z4);
            a1 = as_bf16x8(rA < N ? actIn[(size_t)rA * 8 + 4 + q] : z4);
        }
#pragma unroll
        for (int c = 0; c < 4; c++) {
            float bias = bias1[c];
            f32x4 acc = {bias, bias, bias, bias};
            if (L0) {
                acc = __builtin_amdgcn_mfma_f32_16x16x32_bf16(a0, w1f[c][0], acc, 0, 0, 0);
            } else {
                acc = __builtin_amdgcn_mfma_f32_16x16x32_bf16(a0, w1f[c][0], acc, 0, 0, 0);
                acc = __builtin_amdgcn_mfma_f32_16x16x32_bf16(a1, w1f[c][1], acc, 0, 0, 0);
            }
            int col = c * 16 + m16;
#pragma unroll
            for (int r = 0; r < 4; r++) {
                int row = w * 16 + q * 4 + r;
                mids[row * MSTR + col] = bf16r(fmaxf(acc[r], 0.f));
            }
        }
        __syncthreads();
        int rowM = w * 16 + m16;
        const uint4* midU4 = (const uint4*)mids;
        bf16x8 a20 = as_bf16x8(midU4[rowM * 9 + q]);
        bf16x8 a21 = as_bf16x8(midU4[rowM * 9 + 4 + q]);
        f32x4 accs[4];
#pragma unroll
        for (int c = 0; c < 4; c++) {
            float bias = bias2[c];
            f32x4 acc = {bias, bias, bias, bias};
            acc = __builtin_amdgcn_mfma_f32_16x16x32_bf16(a20, w2f[c][0], acc, 0, 0, 0);
            acc = __builtin_amdgcn_mfma_f32_16x16x32_bf16(a21, w2f[c][1], acc, 0, 0, 0);
            accs[c] = acc;
        }
#pragma unroll
        for (int c = 0; c < 4; c++) {
            int col = c * 16 + m16;
#pragma unroll
            for (int r = 0; r < 4; r++) {
                int row = w * 16 + q * 4 + r;
                float v = accs[c][r];
                if (base + row < N) { s[c] += v; sq[c] += v * v; }
                mids[row * MSTR + col] = bf16r(v);
            }
        }
        __syncthreads();
        for (int i = t; i < 512; i += 256) {
            int row = i >> 3, qo = i & 7;
            int gr = base + row;
            if (gr < N) houtU4[(size_t)gr * 8 + qo] = ((const uint4*)mids)[row * 9 + qo];
        }
    }
    // BN partial reduce -> private global slot (plain stores, no atomics)
    __syncthreads();
    for (int c = 0; c < 4; c++) red[w * 4 + q][c * 16 + m16] = s[c];
    __syncthreads();
    if (t < 64) {
        float S = 0.f;
        for (int i = 0; i < 16; i++) S += red[i][t];
        partS[blockIdx.x * 64 + t] = S;
    }
    __syncthreads();
    for (int c = 0; c < 4; c++) red[w * 4 + q][c * 16 + m16] = sq[c];
    __syncthreads();
    if (t < 64) {
        float S = 0.f;
        for (int i = 0; i < 16; i++) S += red[i][t];
        partQ[blockIdx.x * 64 + t] = S;
    }
}

// ---- reduce per-block BN partials -> bnsum/bnsq (1 block) ----
__global__ __launch_bounds__(256) void bn_reduce(
    const float* __restrict__ partS, const float* __restrict__ partQ,
    float* __restrict__ bnsum, float* __restrict__ bnsq, int nParts) {
    __shared__ float rs[4][64], rq[4][64];
    int t = threadIdx.x, col = t & 63, ro = t >> 6;
    float S = 0.f, Q = 0.f;
    for (int p = ro; p < nParts; p += 4) {
        S += partS[p * 64 + col];
        Q += partQ[p * 64 + col];
    }
    rs[ro][col] = S; rq[ro][col] = Q;
    __syncthreads();
    if (t < 64) {
        bnsum[t] = rs[0][t] + rs[1][t] + rs[2][t] + rs[3][t];
        bnsq[t]  = rq[0][t] + rq[1][t] + rq[2][t] + rq[3][t];
    }
}

// ---- BN apply + mean-pool + output matmul (batch sorted; zero atomics) ----
__device__ __forceinline__ int lowb(const int* __restrict__ a, int n, int v) {
    int lo = 0, hi = n;
    while (lo < hi) {
        int m = (lo + hi) >> 1;
        if (a[m] < v) lo = m + 1; else hi = m;
    }
    return lo;
}

__global__ __launch_bounds__(256) void bn_pool_out(
    const unsigned short* __restrict__ h, const int* __restrict__ batch,
    const float* __restrict__ bnsum, const float* __restrict__ bnsq,
    const float* __restrict__ gamma, const float* __restrict__ beta,
    const float* __restrict__ wout, const float* __restrict__ bout,
    float* __restrict__ out, int N) {
    __shared__ float sc[64], sh[64];
    __shared__ float part[4][64];
    __shared__ float gr[64];
    __shared__ int range[2];
    int g = blockIdx.x, t = threadIdx.x;
    if (t < 64) {
        float mu = bnsum[t] / (float)N;
        float var = bnsq[t] / (float)N - mu * mu;
        float s = gamma[t] * rsqrtf(var + 1e-5f);
        sc[t] = s;
        sh[t] = beta[t] - mu * s;
    }
    if (t == 64) range[0] = lowb(batch, N, g);
    if (t == 65) range[1] = lowb(batch, N, g + 1);
    __syncthreads();
    int s0 = range[0], s1 = range[1];
    int col = t & 63, ro = t >> 6;
    float acc = 0.f;
    for (int n = s0 + ro; n < s1; n += 4) {
        float v = __uint_as_float(((unsigned)h[(size_t)n * 64 + col]) << 16);
        acc += fmaxf(v * sc[col] + sh[col], 0.f);
    }
    part[ro][col] = acc;
    __syncthreads();
    if (t < 64) {
        float S = part[0][t] + part[1][t] + part[2][t] + part[3][t];
        float c = (float)(s1 - s0);
        gr[t] = (c > 0.f) ? S / c : 0.f;
    }
    __syncthreads();
    if (t < 64) {
        float a = bout[t];
        for (int f = 0; f < 64; f++) a += gr[f] * wout[f * 64 + t];
        out[g * 64 + t] = a;
    }
}

extern "C" void kernel_launch(void* const* d_in, const int* in_sizes, int n_in,
                              void* d_out, int out_size, void* d_ws, size_t ws_size,
                              hipStream_t stream) {
    const float* x     = (const float*)d_in[0];
    const int*   ei    = (const int*)d_in[1];
    const int*   batch = (const int*)d_in[2];
    const float* w1_0  = (const float*)d_in[3];
    const float* w1_r  = (const float*)d_in[4];
    const float* b1    = (const float*)d_in[5];
    const float* w2    = (const float*)d_in[6];
    const float* b2    = (const float*)d_in[7];
    const float* gamma = (const float*)d_in[8];
    const float* beta  = (const float*)d_in[9];
    const float* wout  = (const float*)d_in[10];
    const float* bout  = (const float*)d_in[11];
    float* out = (float*)d_out;

    const int N = in_sizes[2];               // 100000
    const int E = in_sizes[1] / 2;           // 3200000
    const int NB = (N + 127) >> 7;           // 782 buckets
    const int nblk = (E + CHUNK - 1) / CHUNK;// 391 scatter blocks
    const int nTiles = (N + 63) >> 6;        // 1563 MLP tiles
    const int nMlpBlocks = 782;              // ~2 tiles/block, ~3 blocks/CU

    // Workspace (~58 MB)
    unsigned short* hbX = (unsigned short*)d_ws;             // N*64 bf16
    unsigned short* hbY = hbX + (size_t)N * 64;              // N*64 bf16
    uint4* h3b = (uint4*)(hbY + (size_t)N * 64);             // N u4
    int* bucketed2 = (int*)(h3b + N);                        // nblk*CHUNK
    int* offsTab   = bucketed2 + (size_t)nblk * CHUNK;       // nblk*1025
    int* csrOut    = offsTab + (size_t)nblk * 1025;          // NB*CAP
    int* rowstart  = csrOut + (size_t)NB * CAP;              // N
    int* rowend    = rowstart + N;                           // N
    float* bnstats = (float*)(rowend + N);                   // 6*64
    float* partS   = bnstats + 384;                          // nMlpBlocks*64
    float* partQ   = partS + (size_t)nMlpBlocks * 64;        // nMlpBlocks*64
    unsigned short* w1T0 = (unsigned short*)(partQ + (size_t)nMlpBlocks * 64); // 64*32
    unsigned short* w1T  = w1T0 + 64 * 32;                   // 2*64*64
    unsigned short* w2T  = w1T + 2 * 64 * 64;                // 3*64*64

    const int* srcv = ei;
    const int* dstv = ei + E;

    prep_weights<<<48, 256, 0, stream>>>(w1_0, w1_r, w2, w1T0, w1T, w2T);

    // --- CSR build ---
    scatter_sort<<<nblk, 512, 0, stream>>>(srcv, dstv, bucketed2, offsTab, E);
    bucket_csr<<<NB, 256, 0, stream>>>(bucketed2, offsTab, csrOut, rowstart, rowend, N, nblk);

    // --- Layer 0 ---
    agg3<<<(N + 255) / 256, 256, 0, stream>>>(x, rowstart, rowend, csrOut, h3b, N);
    mlp_mfma<true><<<nMlpBlocks, 256, 0, stream>>>(h3b, (uint4*)hbX, (const uint4*)w1T0, b1,
                                                   (const uint4*)w2T, b2,
                                                   partS, partQ, N, nTiles);
    bn_reduce<<<1, 256, 0, stream>>>(partS, partQ, bnstats, bnstats + 64, nMlpBlocks);

    // --- Layer 1 ---
    agg64_bn<<<(N + 31) / 32, 256, 0, stream>>>(hbX, rowstart, rowend, csrOut,
                                                bnstats, bnstats + 64, gamma, beta,
                                                (uint4*)hbY, N);
    mlp_mfma<false><<<nMlpBlocks, 256, 0, stream>>>((const uint4*)hbY, (uint4*)hbX,
                                                    (const uint4*)w1T, b1 + 64,
                                                    (const uint4*)(w2T + 4096), b2 + 64,
                                                    partS, partQ, N, nTiles);
    bn_reduce<<<1, 256, 0, stream>>>(partS, partQ, bnstats + 128, bnstats + 192, nMlpBlocks);

    // --- Layer 2 ---
    agg64_bn<<<(N + 31) / 32, 256, 0, stream>>>(hbX, rowstart, rowend, csrOut,
                                                bnstats + 128, bnstats + 192,
                                                gamma + 64, beta + 64, (uint4*)hbY, N);
    mlp_mfma<false><<<nMlpBlocks, 256, 0, stream>>>((const uint4*)hbY, (uint4*)hbX,
                                                    (const uint4*)(w1T + 4096), b1 + 128,
                                                    (const uint4*)(w2T + 8192), b2 + 128,
                                                    partS, partQ, N, nTiles);
    bn_reduce<<<1, 256, 0, stream>>>(partS, partQ, bnstats + 256, bnstats + 320, nMlpBlocks);

    // --- BN2 apply + pool + output matmul ---
    bn_pool_out<<<512, 256, 0, stream>>>(hbX, batch, bnstats + 256, bnstats + 320,
                                         gamma + 128, beta + 128, wout, bout, out, N);
}

// Round 14
// 377.866 us; speedup vs baseline: 1.4152x; 1.4152x over previous
//
#include <hip/hip_runtime.h>

// GIN encoder: N=100k, E=3.2M, G=512, H=64, L=3.
// Round 14: bn_reduce v2 — 64 blocks (one per column), 256 threads each
// (~3 parallel loads/thread + LDS tree). R13's 1-block version was 57us at
// 0.04% occupancy (serial accumulate chains, 255 CUs idle). Everything else
// identical to R13: mlp_mfma v4 (reg weights, no atomics, grid-stride),
// fused agg64_bn, scatter_sort, bucket_csr v3, bn_pool_out.

#define NBMAX 1024
#define CAP 4608
#define CHUNK 8192
#define NBLK_MAX 512
#define MSTR 72   // mids stride in shorts (9 uint4, bank-staggered)

typedef __attribute__((ext_vector_type(8))) short bf16x8;
typedef __attribute__((ext_vector_type(4))) float f32x4;

static __device__ __forceinline__ bf16x8 as_bf16x8(uint4 u) {
    union { uint4 a; bf16x8 b; } x; x.a = u; return x.b;
}
static __device__ __forceinline__ unsigned short bf16r(float v) {
    unsigned u = __float_as_uint(v);
    return (unsigned short)((u + 0x7FFFu + ((u >> 16) & 1u)) >> 16);
}
static __device__ __forceinline__ unsigned bf16pack2(float a, float b) {
    return (unsigned)bf16r(a) | ((unsigned)bf16r(b) << 16);
}

// ---- weight prep: bf16, transposed to [col][k] ----
__global__ void prep_weights(const float* __restrict__ w1_0, const float* __restrict__ w1_r,
                             const float* __restrict__ w2, unsigned short* __restrict__ w1T0,
                             unsigned short* __restrict__ w1T, unsigned short* __restrict__ w2T) {
    int t = blockIdx.x * 256 + threadIdx.x;
    if (t < 64 * 32) {
        int c = t >> 5, k = t & 31;
        w1T0[t] = bf16r(k < 3 ? w1_0[k * 64 + c] : 0.f);
    }
    if (t < 2 * 64 * 64) {
        int l = t >> 12, r = t & 4095, c = r >> 6, k = r & 63;
        w1T[t] = bf16r(w1_r[l * 4096 + k * 64 + c]);
    }
    if (t < 3 * 64 * 64) {
        int l = t >> 12, r = t & 4095, c = r >> 6, k = r & 63;
        w2T[t] = bf16r(w2[l * 4096 + k * 64 + c]);
    }
}

// ---- scatter_sort: block counting-sorts its 8192-edge chunk by bucket ----
__global__ __launch_bounds__(512) void scatter_sort(
    const int* __restrict__ src, const int* __restrict__ dst,
    int* __restrict__ bucketed2, int* __restrict__ offsTab, int E) {
    __shared__ int hist[NBMAX];
    __shared__ int offs[NBMAX];
    __shared__ int stage[CHUNK];
    int t = threadIdx.x, blk = blockIdx.x;
    int e0 = blk * CHUNK, e1 = min(e0 + CHUNK, E);
    int len = e1 - e0;
    hist[t] = 0; hist[t + 512] = 0;
    __syncthreads();
    for (int e = e0 + t; e < e1; e += 512) atomicAdd(&hist[dst[e] >> 7], 1);
    __syncthreads();
    offs[t] = hist[t]; offs[t + 512] = hist[t + 512];
    __syncthreads();
    for (int off = 1; off < 1024; off <<= 1) {
        int v0 = (t >= off) ? offs[t - off] : 0;
        int v1 = offs[t + 512 - off];
        __syncthreads();
        offs[t] += v0;
        offs[t + 512] += v1;
        __syncthreads();
    }
    offs[t] -= hist[t]; offs[t + 512] -= hist[t + 512];
    hist[t] = 0; hist[t + 512] = 0;
    __syncthreads();
    offsTab[blk * 1025 + t] = offs[t];
    offsTab[blk * 1025 + t + 512] = offs[t + 512];
    if (t == 0) offsTab[blk * 1025 + 1024] = len;
    for (int e = e0 + t; e < e1; e += 512) {
        int d = dst[e];
        int bk = d >> 7;
        int r = offs[bk] + atomicAdd(&hist[bk], 1);
        stage[r] = src[e] | ((d & 127) << 20);
    }
    __syncthreads();
    for (int j = t; j < len; j += 512) bucketed2[e0 + j] = stage[j];
}

// ---- bucket_csr v3: binsearch run-gather, counting sort by src-block, then
// by row -> CSR with ~src-ascending rows (L2 locality for agg) ----
__global__ __launch_bounds__(256) void bucket_csr(
    const int* __restrict__ bucketed2, const int* __restrict__ offsTab,
    int* __restrict__ csrOut, int* __restrict__ rowstart, int* __restrict__ rowend,
    int N, int nblk) {
    __shared__ int ein[CAP];
    __shared__ int emid[CAP];
    __shared__ int runs[NBLK_MAX];
    __shared__ int rbeg[NBLK_MAX];
    __shared__ int hist[128];
    __shared__ int base[129];
    int b = blockIdx.x, t = threadIdx.x, node0 = b << 7;
    for (int r = t; r < NBLK_MAX; r += 256) {
        int l = 0, g0 = 0;
        if (r < nblk) {
            int beg = offsTab[r * 1025 + b];
            int end = offsTab[r * 1025 + b + 1];
            l = end - beg;
            g0 = r * CHUNK + beg;
        }
        runs[r] = l;
        rbeg[r] = g0;
    }
    __syncthreads();
    for (int off = 1; off < NBLK_MAX; off <<= 1) {
        int v0 = (t >= off) ? runs[t - off] : 0;
        int v1 = (t + 256 >= off) ? runs[t + 256 - off] : 0;
        __syncthreads();
        runs[t] += v0;
        runs[t + 256] += v1;
        __syncthreads();
    }
    int cnt = min(runs[NBLK_MAX - 1], CAP);
    for (int j = t; j < cnt; j += 256) {
        int lo = 0, hi = nblk - 1;
        while (lo < hi) {
            int m = (lo + hi) >> 1;
            if (runs[m] > j) hi = m; else lo = m + 1;
        }
        int st = lo ? runs[lo - 1] : 0;
        ein[j] = bucketed2[rbeg[lo] + (j - st)];
    }
    // pass 1: group by src block (src>>10)
    if (t < 128) hist[t] = 0;
    __syncthreads();
    for (int j = t; j < cnt; j += 256) atomicAdd(&hist[(ein[j] & 0xFFFFF) >> 10], 1);
    __syncthreads();
    if (t < 128) base[t + 1] = hist[t];
    if (t == 0) base[0] = 0;
    __syncthreads();
    for (int off = 1; off < 128; off <<= 1) {
        int v = 0;
        if (t < 128 && (t + 1) > off) v = base[t + 1 - off];
        __syncthreads();
        if (t < 128 && (t + 1) > off) base[t + 1] += v;
        __syncthreads();
    }
    if (t < 128) hist[t] = 0;
    __syncthreads();
    for (int j = t; j < cnt; j += 256) {
        int p = ein[j];
        int sb = (p & 0xFFFFF) >> 10;
        int pos = base[sb] + atomicAdd(&hist[sb], 1);
        emid[pos] = p;
    }
    __syncthreads();
    // pass 2: counting sort by row
    if (t < 128) hist[t] = 0;
    __syncthreads();
    for (int j = t; j < cnt; j += 256) atomicAdd(&hist[emid[j] >> 20], 1);
    __syncthreads();
    if (t < 128) base[t + 1] = hist[t];
    if (t == 0) base[0] = 0;
    __syncthreads();
    for (int off = 1; off < 128; off <<= 1) {
        int v = 0;
        if (t < 128 && (t + 1) > off) v = base[t + 1 - off];
        __syncthreads();
        if (t < 128 && (t + 1) > off) base[t + 1] += v;
        __syncthreads();
    }
    if (t < 128) {
        int n = node0 + t;
        if (n < N) {
            rowstart[n] = b * CAP + base[t];
            rowend[n] = b * CAP + base[t + 1];
        }
        hist[t] = 0;
    }
    __syncthreads();
    for (int j = t; j < cnt; j += 256) {
        int p = emid[j];
        int local = p >> 20;
        int pos = base[local] + atomicAdd(&hist[local], 1);
        ein[pos] = p & 0xFFFFF;
    }
    __syncthreads();
    for (int j = t; j < cnt; j += 256) csrOut[b * CAP + j] = ein[j];
}

// ---- layer-0 agg (d=3): writes bf16 [n][8]-padded rows (uint4/node) ----
__global__ void agg3(const float* __restrict__ x, const int* __restrict__ rowstart,
                     const int* __restrict__ rowend, const int* __restrict__ csr,
                     uint4* __restrict__ out, int N) {
    int n = blockIdx.x * blockDim.x + threadIdx.x;
    if (n >= N) return;
    float a0 = x[n * 3], a1 = x[n * 3 + 1], a2 = x[n * 3 + 2];
    float b0 = 0.f, b1 = 0.f, b2 = 0.f;
    float c0 = 0.f, c1 = 0.f, c2 = 0.f;
    float d0 = 0.f, d1 = 0.f, d2 = 0.f;
    int s = rowstart[n], e = rowend[n];
    int j = s;
    for (; j + 3 < e; j += 4) {
        int i0 = csr[j], i1 = csr[j + 1], i2 = csr[j + 2], i3 = csr[j + 3];
        a0 += x[i0 * 3]; a1 += x[i0 * 3 + 1]; a2 += x[i0 * 3 + 2];
        b0 += x[i1 * 3]; b1 += x[i1 * 3 + 1]; b2 += x[i1 * 3 + 2];
        c0 += x[i2 * 3]; c1 += x[i2 * 3 + 1]; c2 += x[i2 * 3 + 2];
        d0 += x[i3 * 3]; d1 += x[i3 * 3 + 1]; d2 += x[i3 * 3 + 2];
    }
    for (; j < e; j++) {
        int nb = csr[j];
        a0 += x[nb * 3]; a1 += x[nb * 3 + 1]; a2 += x[nb * 3 + 2];
    }
    float s0 = a0 + b0 + c0 + d0, s1 = a1 + b1 + c1 + d1, s2 = a2 + b2 + c2 + d2;
    out[n] = make_uint4(bf16pack2(s0, s1), bf16pack2(s2, 0.f), 0u, 0u);
}

// bf16x2-packed accumulate of relu(v*sc+sh)
__device__ __forceinline__ void accum_bf16(const uint4 u,
                                           const float4 scA, const float4 scB,
                                           const float4 shA, const float4 shB,
                                           float* __restrict__ a) {
    a[0] += fmaxf(__uint_as_float(u.x << 16) * scA.x + shA.x, 0.f);
    a[1] += fmaxf(__uint_as_float(u.x & 0xFFFF0000u) * scA.y + shA.y, 0.f);
    a[2] += fmaxf(__uint_as_float(u.y << 16) * scA.z + shA.z, 0.f);
    a[3] += fmaxf(__uint_as_float(u.y & 0xFFFF0000u) * scA.w + shA.w, 0.f);
    a[4] += fmaxf(__uint_as_float(u.z << 16) * scB.x + shB.x, 0.f);
    a[5] += fmaxf(__uint_as_float(u.z & 0xFFFF0000u) * scB.y + shB.y, 0.f);
    a[6] += fmaxf(__uint_as_float(u.w << 16) * scB.z + shB.z, 0.f);
    a[7] += fmaxf(__uint_as_float(u.w & 0xFFFF0000u) * scB.w + shB.w, 0.f);
}

// ---- layers 1-2 agg + fused BN apply; bf16 in, bf16 out ----
__global__ __launch_bounds__(256) void agg64_bn(
    const unsigned short* __restrict__ h, const int* __restrict__ rowstart,
    const int* __restrict__ rowend, const int* __restrict__ csr,
    const float* __restrict__ bnsum, const float* __restrict__ bnsq,
    const float* __restrict__ gamma, const float* __restrict__ beta,
    uint4* __restrict__ out, int N) {
    __shared__ float scs[64], shs[64];
    int t = threadIdx.x;
    if (t < 64) {
        float mu = bnsum[t] / (float)N;
        float var = bnsq[t] / (float)N - mu * mu;
        float s = gamma[t] * rsqrtf(var + 1e-5f);
        scs[t] = s;
        shs[t] = beta[t] - mu * s;
    }
    __syncthreads();
    int g = t >> 3, l = t & 7;
    int n = blockIdx.x * 32 + g;
    if (n >= N) return;
    int c0 = l * 8;
    float4 scA = *(const float4*)&scs[c0], scB = *(const float4*)&scs[c0 + 4];
    float4 shA = *(const float4*)&shs[c0], shB = *(const float4*)&shs[c0 + 4];
    const uint4* hr = (const uint4*)h;
    float A[8] = {0,0,0,0,0,0,0,0};
    float B[8] = {0,0,0,0,0,0,0,0};
    uint4 self = hr[(size_t)n * 8 + l];
    accum_bf16(self, scA, scB, shA, shB, A);
    int s = rowstart[n], e = rowend[n];
    int j = s;
    for (; j + 3 < e; j += 4) {
        int i0 = csr[j], i1 = csr[j + 1], i2 = csr[j + 2], i3 = csr[j + 3];
        uint4 w0 = hr[(size_t)i0 * 8 + l];
        uint4 w1 = hr[(size_t)i1 * 8 + l];
        uint4 w2 = hr[(size_t)i2 * 8 + l];
        uint4 w3 = hr[(size_t)i3 * 8 + l];
        accum_bf16(w0, scA, scB, shA, shB, A);
        accum_bf16(w1, scA, scB, shA, shB, B);
        accum_bf16(w2, scA, scB, shA, shB, A);
        accum_bf16(w3, scA, scB, shA, shB, B);
    }
    for (; j < e; j++) {
        uint4 w = hr[(size_t)csr[j] * 8 + l];
        accum_bf16(w, scA, scB, shA, shB, A);
    }
    uint4 o;
    o.x = bf16pack2(A[0] + B[0], A[1] + B[1]);
    o.y = bf16pack2(A[2] + B[2], A[3] + B[3]);
    o.z = bf16pack2(A[4] + B[4], A[5] + B[5]);
    o.w = bf16pack2(A[6] + B[6], A[7] + B[7]);
    out[(size_t)n * 8 + l] = o;
}

// ---- MLP on MFMA v4: grid-stride tiles, weights in registers, coalesced
// LDS-staged epilogue, BN partials -> private global slots (NO atomics) ----
template <bool L0>
__global__ __launch_bounds__(256) void mlp_mfma(
    const uint4* __restrict__ actIn,
    uint4* __restrict__ houtU4,
    const uint4* __restrict__ w1Tu,
    const float* __restrict__ b1,
    const uint4* __restrict__ w2Tu,
    const float* __restrict__ b2,
    float* __restrict__ partS, float* __restrict__ partQ, int N, int nTiles) {
    __shared__ __align__(16) unsigned short mids[64 * MSTR];
    __shared__ float red[16][64];
    int t = threadIdx.x;
    int w = t >> 6, l = t & 63;
    int m16 = l & 15, q = l >> 4;
    const uint4 z4 = make_uint4(0, 0, 0, 0);
    bf16x8 w1f[4][2], w2f[4][2];
    float bias1[4], bias2[4];
#pragma unroll
    for (int c = 0; c < 4; c++) {
        int col = c * 16 + m16;
        if (L0) {
            w1f[c][0] = as_bf16x8(w1Tu[col * 4 + q]);
        } else {
            w1f[c][0] = as_bf16x8(w1Tu[col * 8 + q]);
            w1f[c][1] = as_bf16x8(w1Tu[col * 8 + 4 + q]);
        }
        w2f[c][0] = as_bf16x8(w2Tu[col * 8 + q]);
        w2f[c][1] = as_bf16x8(w2Tu[col * 8 + 4 + q]);
        bias1[c] = b1[col];
        bias2[c] = b2[col];
    }
    float s[4] = {0, 0, 0, 0}, sq[4] = {0, 0, 0, 0};
    for (int tile = blockIdx.x; tile < nTiles; tile += gridDim.x) {
        int base = tile * 64;
        __syncthreads();  // protect mids vs previous iteration's store loop
        int rA = base + w * 16 + m16;
        bf16x8 a0, a1;
        if (L0) {
            a0 = as_bf16x8((rA < N && q == 0) ? actIn[rA] : z4);
        } else {
            a0 = as_bf16x8(rA < N ? actIn[(size_t)rA * 8 + q] : z4);
            a1 = as_bf16x8(rA < N ? actIn[(size_t)rA * 8 + 4 + q] : z4);
        }
#pragma unroll
        for (int c = 0; c < 4; c++) {
            float bias = bias1[c];
            f32x4 acc = {bias, bias, bias, bias};
            if (L0) {
                acc = __builtin_amdgcn_mfma_f32_16x16x32_bf16(a0, w1f[c][0], acc, 0, 0, 0);
            } else {
                acc = __builtin_amdgcn_mfma_f32_16x16x32_bf16(a0, w1f[c][0], acc, 0, 0, 0);
                acc = __builtin_amdgcn_mfma_f32_16x16x32_bf16(a1, w1f[c][1], acc, 0, 0, 0);
            }
            int col = c * 16 + m16;
#pragma unroll
            for (int r = 0; r < 4; r++) {
                int row = w * 16 + q * 4 + r;
                mids[row * MSTR + col] = bf16r(fmaxf(acc[r], 0.f));
            }
        }
        __syncthreads();
        int rowM = w * 16 + m16;
        const uint4* midU4 = (const uint4*)mids;
        bf16x8 a20 = as_bf16x8(midU4[rowM * 9 + q]);
        bf16x8 a21 = as_bf16x8(midU4[rowM * 9 + 4 + q]);
        f32x4 accs[4];
#pragma unroll
        for (int c = 0; c < 4; c++) {
            float bias = bias2[c];
            f32x4 acc = {bias, bias, bias, bias};
            acc = __builtin_amdgcn_mfma_f32_16x16x32_bf16(a20, w2f[c][0], acc, 0, 0, 0);
            acc = __builtin_amdgcn_mfma_f32_16x16x32_bf16(a21, w2f[c][1], acc, 0, 0, 0);
            accs[c] = acc;
        }
#pragma unroll
        for (int c = 0; c < 4; c++) {
            int col = c * 16 + m16;
#pragma unroll
            for (int r = 0; r < 4; r++) {
                int row = w * 16 + q * 4 + r;
                float v = accs[c][r];
                if (base + row < N) { s[c] += v; sq[c] += v * v; }
                mids[row * MSTR + col] = bf16r(v);
            }
        }
        __syncthreads();
        for (int i = t; i < 512; i += 256) {
            int row = i >> 3, qo = i & 7;
            int gr = base + row;
            if (gr < N) houtU4[(size_t)gr * 8 + qo] = ((const uint4*)mids)[row * 9 + qo];
        }
    }
    // BN partial reduce -> private global slot (plain stores, no atomics)
    __syncthreads();
    for (int c = 0; c < 4; c++) red[w * 4 + q][c * 16 + m16] = s[c];
    __syncthreads();
    if (t < 64) {
        float S = 0.f;
        for (int i = 0; i < 16; i++) S += red[i][t];
        partS[blockIdx.x * 64 + t] = S;
    }
    __syncthreads();
    for (int c = 0; c < 4; c++) red[w * 4 + q][c * 16 + m16] = sq[c];
    __syncthreads();
    if (t < 64) {
        float S = 0.f;
        for (int i = 0; i < 16; i++) S += red[i][t];
        partQ[blockIdx.x * 64 + t] = S;
    }
}

// ---- bn_reduce v2: 64 blocks, block b reduces column b over nParts ----
__global__ __launch_bounds__(256) void bn_reduce(
    const float* __restrict__ partS, const float* __restrict__ partQ,
    float* __restrict__ bnsum, float* __restrict__ bnsq, int nParts) {
    __shared__ float rs[256], rq[256];
    int b = blockIdx.x, t = threadIdx.x;
    float S = 0.f, Q = 0.f;
    for (int p = t; p < nParts; p += 256) {
        S += partS[p * 64 + b];
        Q += partQ[p * 64 + b];
    }
    rs[t] = S; rq[t] = Q;
    __syncthreads();
    for (int off = 128; off > 0; off >>= 1) {
        if (t < off) { rs[t] += rs[t + off]; rq[t] += rq[t + off]; }
        __syncthreads();
    }
    if (t == 0) { bnsum[b] = rs[0]; bnsq[b] = rq[0]; }
}

// ---- BN apply + mean-pool + output matmul (batch sorted; zero atomics) ----
__device__ __forceinline__ int lowb(const int* __restrict__ a, int n, int v) {
    int lo = 0, hi = n;
    while (lo < hi) {
        int m = (lo + hi) >> 1;
        if (a[m] < v) lo = m + 1; else hi = m;
    }
    return lo;
}

__global__ __launch_bounds__(256) void bn_pool_out(
    const unsigned short* __restrict__ h, const int* __restrict__ batch,
    const float* __restrict__ bnsum, const float* __restrict__ bnsq,
    const float* __restrict__ gamma, const float* __restrict__ beta,
    const float* __restrict__ wout, const float* __restrict__ bout,
    float* __restrict__ out, int N) {
    __shared__ float sc[64], sh[64];
    __shared__ float part[4][64];
    __shared__ float gr[64];
    __shared__ int range[2];
    int g = blockIdx.x, t = threadIdx.x;
    if (t < 64) {
        float mu = bnsum[t] / (float)N;
        float var = bnsq[t] / (float)N - mu * mu;
        float s = gamma[t] * rsqrtf(var + 1e-5f);
        sc[t] = s;
        sh[t] = beta[t] - mu * s;
    }
    if (t == 64) range[0] = lowb(batch, N, g);
    if (t == 65) range[1] = lowb(batch, N, g + 1);
    __syncthreads();
    int s0 = range[0], s1 = range[1];
    int col = t & 63, ro = t >> 6;
    float acc = 0.f;
    for (int n = s0 + ro; n < s1; n += 4) {
        float v = __uint_as_float(((unsigned)h[(size_t)n * 64 + col]) << 16);
        acc += fmaxf(v * sc[col] + sh[col], 0.f);
    }
    part[ro][col] = acc;
    __syncthreads();
    if (t < 64) {
        float S = part[0][t] + part[1][t] + part[2][t] + part[3][t];
        float c = (float)(s1 - s0);
        gr[t] = (c > 0.f) ? S / c : 0.f;
    }
    __syncthreads();
    if (t < 64) {
        float a = bout[t];
        for (int f = 0; f < 64; f++) a += gr[f] * wout[f * 64 + t];
        out[g * 64 + t] = a;
    }
}

extern "C" void kernel_launch(void* const* d_in, const int* in_sizes, int n_in,
                              void* d_out, int out_size, void* d_ws, size_t ws_size,
                              hipStream_t stream) {
    const float* x     = (const float*)d_in[0];
    const int*   ei    = (const int*)d_in[1];
    const int*   batch = (const int*)d_in[2];
    const float* w1_0  = (const float*)d_in[3];
    const float* w1_r  = (const float*)d_in[4];
    const float* b1    = (const float*)d_in[5];
    const float* w2    = (const float*)d_in[6];
    const float* b2    = (const float*)d_in[7];
    const float* gamma = (const float*)d_in[8];
    const float* beta  = (const float*)d_in[9];
    const float* wout  = (const float*)d_in[10];
    const float* bout  = (const float*)d_in[11];
    float* out = (float*)d_out;

    const int N = in_sizes[2];               // 100000
    const int E = in_sizes[1] / 2;           // 3200000
    const int NB = (N + 127) >> 7;           // 782 buckets
    const int nblk = (E + CHUNK - 1) / CHUNK;// 391 scatter blocks
    const int nTiles = (N + 63) >> 6;        // 1563 MLP tiles
    const int nMlpBlocks = 782;              // ~2 tiles/block, ~3 blocks/CU

    // Workspace (~58 MB)
    unsigned short* hbX = (unsigned short*)d_ws;             // N*64 bf16
    unsigned short* hbY = hbX + (size_t)N * 64;              // N*64 bf16
    uint4* h3b = (uint4*)(hbY + (size_t)N * 64);             // N u4
    int* bucketed2 = (int*)(h3b + N);                        // nblk*CHUNK
    int* offsTab   = bucketed2 + (size_t)nblk * CHUNK;       // nblk*1025
    int* csrOut    = offsTab + (size_t)nblk * 1025;          // NB*CAP
    int* rowstart  = csrOut + (size_t)NB * CAP;              // N
    int* rowend    = rowstart + N;                           // N
    float* bnstats = (float*)(rowend + N);                   // 6*64
    float* partS   = bnstats + 384;                          // nMlpBlocks*64
    float* partQ   = partS + (size_t)nMlpBlocks * 64;        // nMlpBlocks*64
    unsigned short* w1T0 = (unsigned short*)(partQ + (size_t)nMlpBlocks * 64); // 64*32
    unsigned short* w1T  = w1T0 + 64 * 32;                   // 2*64*64
    unsigned short* w2T  = w1T + 2 * 64 * 64;                // 3*64*64

    const int* srcv = ei;
    const int* dstv = ei + E;

    prep_weights<<<48, 256, 0, stream>>>(w1_0, w1_r, w2, w1T0, w1T, w2T);

    // --- CSR build ---
    scatter_sort<<<nblk, 512, 0, stream>>>(srcv, dstv, bucketed2, offsTab, E);
    bucket_csr<<<NB, 256, 0, stream>>>(bucketed2, offsTab, csrOut, rowstart, rowend, N, nblk);

    // --- Layer 0 ---
    agg3<<<(N + 255) / 256, 256, 0, stream>>>(x, rowstart, rowend, csrOut, h3b, N);
    mlp_mfma<true><<<nMlpBlocks, 256, 0, stream>>>(h3b, (uint4*)hbX, (const uint4*)w1T0, b1,
                                                   (const uint4*)w2T, b2,
                                                   partS, partQ, N, nTiles);
    bn_reduce<<<64, 256, 0, stream>>>(partS, partQ, bnstats, bnstats + 64, nMlpBlocks);

    // --- Layer 1 ---
    agg64_bn<<<(N + 31) / 32, 256, 0, stream>>>(hbX, rowstart, rowend, csrOut,
                                                bnstats, bnstats + 64, gamma, beta,
                                                (uint4*)hbY, N);
    mlp_mfma<false><<<nMlpBlocks, 256, 0, stream>>>((const uint4*)hbY, (uint4*)hbX,
                                                    (const uint4*)w1T, b1 + 64,
                                                    (const uint4*)(w2T + 4096), b2 + 64,
                                                    partS, partQ, N, nTiles);
    bn_reduce<<<64, 256, 0, stream>>>(partS, partQ, bnstats + 128, bnstats + 192, nMlpBlocks);

    // --- Layer 2 ---
    agg64_bn<<<(N + 31) / 32, 256, 0, stream>>>(hbX, rowstart, rowend, csrOut,
                                                bnstats + 128, bnstats + 192,
                                                gamma + 64, beta + 64, (uint4*)hbY, N);
    mlp_mfma<false><<<nMlpBlocks, 256, 0, stream>>>((const uint4*)hbY, (uint4*)hbX,
                                                    (const uint4*)(w1T + 4096), b1 + 128,
                                                    (const uint4*)(w2T + 8192), b2 + 128,
                                                    partS, partQ, N, nTiles);
    bn_reduce<<<64, 256, 0, stream>>>(partS, partQ, bnstats + 256, bnstats + 320, nMlpBlocks);

    // --- BN2 apply + pool + output matmul ---
    bn_pool_out<<<512, 256, 0, stream>>>(hbX, batch, bnstats + 256, bnstats + 320,
                                         gamma + 128, beta + 128, wout, bout, out, N);
}